// Round 1
// baseline (440.276 us; speedup 1.0000x reference)
//
#include <hip/hip_runtime.h>

#define B_    2048
#define S_    512
#define NFT_  64
#define K1_   16
#define K2_   12
#define NOUT_ 32
#define ROWS_PER_BLK 128
#define CHUNKS 4              // S_ / ROWS_PER_BLK
#define XPAD 68               // LDS row stride in floats: ==4 mod 32, 16B-aligned

// Kernel 1: pooled1[blk][k] = sum over active rows in chunk of relu(x @ W1 + b1)
__global__ __launch_bounds__(128) void k1_embed_pool(
    const float* __restrict__ X, const int* __restrict__ setSizes,
    const float* __restrict__ W1, const float* __restrict__ b1,
    float* __restrict__ part)
{
    __shared__ __align__(16) float xs[ROWS_PER_BLK][XPAD];
    __shared__ __align__(16) float w1t[K1_][NFT_];   // transposed: w1t[k][f]
    __shared__ float b1s[K1_];
    __shared__ float red[2][K1_];

    const int t     = threadIdx.x;
    const int blk   = blockIdx.x;
    const int b     = blk >> 2;
    const int chunk = blk & 3;
    const int s0    = chunk * ROWS_PER_BLK;

    // --- stage W1 transposed (coalesced global float4 read) ---
    {
        const float4* W14 = (const float4*)W1;       // W1 is [64][16] row-major
        #pragma unroll
        for (int i = 0; i < 2; ++i) {
            int idx4 = t + 128 * i;                  // 0..255
            float4 v = W14[idx4];
            int e = idx4 * 4;                        // e = f*16 + k0
            int f = e >> 4;
            int k = e & 15;                          // k0 in {0,4,8,12}
            w1t[k + 0][f] = v.x;
            w1t[k + 1][f] = v.y;
            w1t[k + 2][f] = v.z;
            w1t[k + 3][f] = v.w;
        }
    }
    if (t < K1_) b1s[t] = b1[t];

    int n = setSizes[b];
    int n_local = n - s0;
    if (n_local < 0) n_local = 0;
    if (n_local > ROWS_PER_BLK) n_local = ROWS_PER_BLK;

    // --- stage active X rows into LDS (coalesced; masked rows never loaded) ---
    {
        const float4* X4 = (const float4*)X + ((size_t)b * S_ + s0) * (NFT_ / 4);
        const int lim = n_local * (NFT_ / 4);
        #pragma unroll
        for (int i = 0; i < 16; ++i) {
            int idx = t + 128 * i;
            if (idx < lim) {
                float4 v = X4[idx];
                int r = idx >> 4;
                int c = (idx & 15) * 4;
                *(float4*)&xs[r][c] = v;
            }
        }
    }
    __syncthreads();

    float pool[K1_];
    #pragma unroll
    for (int k = 0; k < K1_; ++k) pool[k] = 0.f;

    if (t < n_local) {
        float x[NFT_];
        #pragma unroll
        for (int j = 0; j < 16; ++j) {
            float4 v = *(const float4*)&xs[t][4 * j];
            x[4 * j + 0] = v.x; x[4 * j + 1] = v.y;
            x[4 * j + 2] = v.z; x[4 * j + 3] = v.w;
        }
        #pragma unroll
        for (int k = 0; k < K1_; ++k) {
            float acc = b1s[k];
            #pragma unroll
            for (int j = 0; j < 16; ++j) {
                float4 w = *(const float4*)&w1t[k][4 * j];  // wave-uniform broadcast
                acc += x[4 * j + 0] * w.x + x[4 * j + 1] * w.y
                     + x[4 * j + 2] * w.z + x[4 * j + 3] * w.w;
            }
            pool[k] = acc > 0.f ? acc : 0.f;                // relu
        }
    }

    // --- block reduction: wave shuffle tree, then cross-wave via LDS ---
    #pragma unroll
    for (int k = 0; k < K1_; ++k) {
        float v = pool[k];
        #pragma unroll
        for (int off = 32; off > 0; off >>= 1) v += __shfl_xor(v, off, 64);
        pool[k] = v;
    }
    const int wave = t >> 6;
    const int lane = t & 63;
    if (lane == 0) {
        #pragma unroll
        for (int k = 0; k < K1_; ++k) red[wave][k] = pool[k];
    }
    __syncthreads();
    if (t < K1_) part[(size_t)blk * K1_ + t] = red[0][t] + red[1][t];
}

// Kernel 2: out[b][o] = pooled1[b] @ (W2@W3) + n_b*(b2@W3) + b3
__global__ __launch_bounds__(256) void k2_out(
    const int* __restrict__ setSizes,
    const float* __restrict__ W2, const float* __restrict__ b2,
    const float* __restrict__ W3, const float* __restrict__ b3,
    const float* __restrict__ part, float* __restrict__ out)
{
    __shared__ float w23[K1_ * NOUT_];   // 512
    __shared__ float bb[NOUT_];
    const int t = threadIdx.x;

    for (int e = t; e < K1_ * NOUT_; e += 256) {
        int k = e >> 5, o = e & 31;
        float s = 0.f;
        #pragma unroll
        for (int j = 0; j < K2_; ++j) s += W2[k * K2_ + j] * W3[j * NOUT_ + o];
        w23[e] = s;
    }
    if (t < NOUT_) {
        float s = 0.f;
        #pragma unroll
        for (int j = 0; j < K2_; ++j) s += b2[j] * W3[j * NOUT_ + t];
        bb[t] = s;
    }
    __syncthreads();

    const int gid = blockIdx.x * 256 + t;
    const int b = gid >> 5, o = gid & 31;
    const float* p0 = part + (size_t)b * CHUNKS * K1_;
    float r = 0.f;
    #pragma unroll
    for (int k = 0; k < K1_; ++k) {
        float pk = p0[k] + p0[K1_ + k] + p0[2 * K1_ + k] + p0[3 * K1_ + k];
        r += pk * w23[k * NOUT_ + o];
    }
    out[gid] = r + (float)setSizes[b] * bb[o] + b3[o];
}

extern "C" void kernel_launch(void* const* d_in, const int* in_sizes, int n_in,
                              void* d_out, int out_size, void* d_ws, size_t ws_size,
                              hipStream_t stream) {
    const float* X        = (const float*)d_in[0];
    const int*   setSizes = (const int*)  d_in[1];
    const float* W1       = (const float*)d_in[2];
    const float* b1       = (const float*)d_in[3];
    const float* W2       = (const float*)d_in[4];
    const float* b2       = (const float*)d_in[5];
    const float* W3       = (const float*)d_in[6];
    const float* b3       = (const float*)d_in[7];
    float* out  = (float*)d_out;
    float* part = (float*)d_ws;          // [8192][16] f32 = 512 KB

    hipLaunchKernelGGL(k1_embed_pool, dim3(B_ * CHUNKS), dim3(128), 0, stream,
                       X, setSizes, W1, b1, part);
    hipLaunchKernelGGL(k2_out, dim3(B_ * NOUT_ / 256), dim3(256), 0, stream,
                       setSizes, W2, b2, W3, b3, part, out);
}

// Round 2
// 380.756 us; speedup vs baseline: 1.1563x; 1.1563x over previous
//
#include <hip/hip_runtime.h>

#define B_    2048
#define S_    512
#define NFT_  64
#define K1_   16
#define K2_   12
#define NOUT_ 32
#define ROWS_PER_BLK 128
#define CHUNKS 4              // S_ / ROWS_PER_BLK
#define XPAD 68               // row stride in floats: 16B-aligned, rows r..r+3 hit disjoint bank-quads

// Kernel 1: part[blk][k] = sum over active rows in chunk of relu(x @ W1 + b1)[k]
// Layout: 256 threads = 4 waves; lane = g*16+k (g=row-group 0..3, k=output col).
// W1 column k lives in 64 VGPRs per lane (no LDS w reads); x rows broadcast from LDS.
__global__ __launch_bounds__(256) void k1_embed_pool(
    const float* __restrict__ X, const int* __restrict__ setSizes,
    const float* __restrict__ W1, const float* __restrict__ b1,
    float* __restrict__ part)
{
    __shared__ __align__(16) float xs[ROWS_PER_BLK][XPAD];
    __shared__ float red[4][K1_];

    const int t    = threadIdx.x;
    const int blk  = blockIdx.x;
    const int b    = blk >> 2;
    const int s0   = (blk & 3) * ROWS_PER_BLK;
    const int wave = t >> 6;
    const int lane = t & 63;
    const int g    = lane >> 4;   // row group within wave
    const int k    = lane & 15;   // owned output column

    int n = setSizes[b];
    int n_local = n - s0;
    n_local = n_local < 0 ? 0 : (n_local > ROWS_PER_BLK ? ROWS_PER_BLK : n_local);

    // --- W1 column k -> 64 VGPRs (4 KB total, L2-resident after first blocks) ---
    float w[NFT_];
    #pragma unroll
    for (int f = 0; f < NFT_; ++f) w[f] = W1[f * K1_ + k];
    const float bk = b1[k];

    // --- stage active X rows coalesced into LDS (masked rows never loaded) ---
    {
        const float4* X4 = (const float4*)X + ((size_t)b * S_ + s0) * (NFT_ / 4);
        const int lim = n_local * (NFT_ / 4);
        #pragma unroll
        for (int i = 0; i < 8; ++i) {
            int idx = t + 256 * i;
            if (idx < lim) {
                float4 v = X4[idx];
                *(float4*)&xs[idx >> 4][(idx & 15) * 4] = v;
            }
        }
    }
    __syncthreads();

    // --- compute: wave handles rows [wave*32, wave*32+32); 4 rows per step ---
    float pool = 0.f;
    const int base = wave * 32;
    int m = n_local - base;
    m = m < 0 ? 0 : (m > 32 ? 32 : m);
    const int steps = (m + 3) >> 2;
    for (int s = 0; s < steps; ++s) {
        const int r = base + s * 4 + g;
        float acc = bk;
        #pragma unroll
        for (int j = 0; j < 16; ++j) {
            // 4 distinct addrs (one per group), 16-way broadcast each; disjoint bank-quads
            float4 x4 = *(const float4*)&xs[r][4 * j];
            acc += x4.x * w[4*j+0] + x4.y * w[4*j+1]
                 + x4.z * w[4*j+2] + x4.w * w[4*j+3];
        }
        if (s * 4 + g < m) pool += (acc > 0.f ? acc : 0.f);  // relu + masked pool
    }

    // --- reduce: 2 shuffles (over g), then cross-wave via tiny LDS ---
    pool += __shfl_xor(pool, 16, 64);
    pool += __shfl_xor(pool, 32, 64);
    if (lane < K1_) red[wave][lane] = pool;
    __syncthreads();
    if (t < K1_)
        part[(size_t)blk * K1_ + t] = red[0][t] + red[1][t] + red[2][t] + red[3][t];
}

// Kernel 2: out[b][o] = pooled1[b] @ (W2@W3) + n_b*(b2@W3) + b3
__global__ __launch_bounds__(256) void k2_out(
    const int* __restrict__ setSizes,
    const float* __restrict__ W2, const float* __restrict__ b2,
    const float* __restrict__ W3, const float* __restrict__ b3,
    const float* __restrict__ part, float* __restrict__ out)
{
    __shared__ float w23[K1_ * NOUT_];
    __shared__ float bb[NOUT_];
    const int t = threadIdx.x;

    for (int e = t; e < K1_ * NOUT_; e += 256) {
        int k = e >> 5, o = e & 31;
        float s = 0.f;
        #pragma unroll
        for (int j = 0; j < K2_; ++j) s += W2[k * K2_ + j] * W3[j * NOUT_ + o];
        w23[e] = s;
    }
    if (t < NOUT_) {
        float s = 0.f;
        #pragma unroll
        for (int j = 0; j < K2_; ++j) s += b2[j] * W3[j * NOUT_ + t];
        bb[t] = s;
    }
    __syncthreads();

    const int gid = blockIdx.x * 256 + t;
    const int b = gid >> 5, o = gid & 31;
    const float* p0 = part + (size_t)b * CHUNKS * K1_;
    float r = 0.f;
    #pragma unroll
    for (int k = 0; k < K1_; ++k) {
        float pk = p0[k] + p0[K1_ + k] + p0[2 * K1_ + k] + p0[3 * K1_ + k];
        r += pk * w23[k * NOUT_ + o];
    }
    out[gid] = r + (float)setSizes[b] * bb[o] + b3[o];
}

extern "C" void kernel_launch(void* const* d_in, const int* in_sizes, int n_in,
                              void* d_out, int out_size, void* d_ws, size_t ws_size,
                              hipStream_t stream) {
    const float* X        = (const float*)d_in[0];
    const int*   setSizes = (const int*)  d_in[1];
    const float* W1       = (const float*)d_in[2];
    const float* b1       = (const float*)d_in[3];
    const float* W2       = (const float*)d_in[4];
    const float* b2       = (const float*)d_in[5];
    const float* W3       = (const float*)d_in[6];
    const float* b3       = (const float*)d_in[7];
    float* out  = (float*)d_out;
    float* part = (float*)d_ws;          // [B*CHUNKS][16] f32 = 512 KB

    hipLaunchKernelGGL(k1_embed_pool, dim3(B_ * CHUNKS), dim3(256), 0, stream,
                       X, setSizes, W1, b1, part);
    hipLaunchKernelGGL(k2_out, dim3(B_ * NOUT_ / 256), dim3(256), 0, stream,
                       setSizes, W2, b2, W3, b3, part, out);
}

// Round 3
// 343.906 us; speedup vs baseline: 1.2802x; 1.1072x over previous
//
#include <hip/hip_runtime.h>

#define B_    2048
#define S_    512
#define NFT_  64
#define K1_   16
#define K2_   12
#define NOUT_ 32

typedef __attribute__((ext_vector_type(8))) short bf16x8;  // 8 bf16 = 4 VGPRs
typedef __attribute__((ext_vector_type(4))) float f32x4;

// fp32 -> bf16 bits, round-to-nearest-even
static __device__ __forceinline__ short f2bf(float x) {
    union { float f; unsigned u; } v; v.f = x;
    unsigned r = v.u + 0x7FFF + ((v.u >> 16) & 1);
    return (short)(r >> 16);
}

// One block per batch b. 4 waves; wave w handles 16-row tiles t = w, w+4, ...
// Tiles entirely beyond setSizes[b] are never loaded (HBM skip).
// A-frag (16x16x32): lane holds A[row=lane&15][k=(lane>>4)*8+j]  -> direct global loads
// B-frag:            lane holds B[k=(lane>>4)*8+j][col=lane&15]  -> W1 in 8 VGPRs
// C-frag:            lane reg i -> row=(lane>>4)*4+i, col=lane&15
__global__ __launch_bounds__(256) void setembed_fused(
    const float* __restrict__ X, const int* __restrict__ setSizes,
    const float* __restrict__ W1, const float* __restrict__ b1,
    const float* __restrict__ W2, const float* __restrict__ b2,
    const float* __restrict__ W3, const float* __restrict__ b3,
    float* __restrict__ out)
{
    __shared__ float red[4][K1_];

    const int t    = threadIdx.x;
    const int b    = blockIdx.x;
    const int wave = t >> 6;
    const int lane = t & 63;
    const int m    = lane & 15;   // A-row within tile; also C-col
    const int quad = lane >> 4;

    const int n = setSizes[b];

    // ---- W1 as two B-fragments (K-steps 0/1); bias for owned column ----
    bf16x8 wf0, wf1;
    #pragma unroll
    for (int j = 0; j < 8; ++j) {
        wf0[j] = f2bf(W1[(     quad * 8 + j) * K1_ + m]);
        wf1[j] = f2bf(W1[(32 + quad * 8 + j) * K1_ + m]);
    }
    const float bk = b1[m];

    float pool = 0.f;
    const int ntiles = (n + 15) >> 4;
    const float* Xb = X + (size_t)b * S_ * NFT_;

    for (int tl = wave; tl < ntiles; tl += 4) {
        const int r0 = tl * 16;
        const float* rowp = Xb + (size_t)(r0 + m) * NFT_ + quad * 8;
        float4 p0 = *(const float4*)(rowp);
        float4 p1 = *(const float4*)(rowp + 4);
        float4 p2 = *(const float4*)(rowp + 32);
        float4 p3 = *(const float4*)(rowp + 36);

        bf16x8 a0, a1;
        a0[0] = f2bf(p0.x); a0[1] = f2bf(p0.y); a0[2] = f2bf(p0.z); a0[3] = f2bf(p0.w);
        a0[4] = f2bf(p1.x); a0[5] = f2bf(p1.y); a0[6] = f2bf(p1.z); a0[7] = f2bf(p1.w);
        a1[0] = f2bf(p2.x); a1[1] = f2bf(p2.y); a1[2] = f2bf(p2.z); a1[3] = f2bf(p2.w);
        a1[4] = f2bf(p3.x); a1[5] = f2bf(p3.y); a1[6] = f2bf(p3.z); a1[7] = f2bf(p3.w);

        f32x4 c = {0.f, 0.f, 0.f, 0.f};
        c = __builtin_amdgcn_mfma_f32_16x16x32_bf16(a0, wf0, c, 0, 0, 0);
        c = __builtin_amdgcn_mfma_f32_16x16x32_bf16(a1, wf1, c, 0, 0, 0);

        #pragma unroll
        for (int i = 0; i < 4; ++i) {
            float h = c[i] + bk;
            h = h > 0.f ? h : 0.f;                 // relu
            int row = r0 + quad * 4 + i;
            pool += (row < n) ? h : 0.f;           // masked sum-pool
        }
    }

    // reduce pool over the 4 quad-groups (same col), then across waves
    pool += __shfl_xor(pool, 16, 64);
    pool += __shfl_xor(pool, 32, 64);
    if (lane < K1_) red[wave][lane] = pool;
    __syncthreads();

    // epilogue: out[b][o] = pooled @ (W2@W3) + n*(b2@W3) + b3   (weights L2-hot)
    if (t < NOUT_) {
        const int o = t;
        float r = 0.f;
        #pragma unroll
        for (int k = 0; k < K1_; ++k) {
            float pk = red[0][k] + red[1][k] + red[2][k] + red[3][k];
            float w23 = 0.f;
            #pragma unroll
            for (int j = 0; j < K2_; ++j)
                w23 += W2[k * K2_ + j] * W3[j * NOUT_ + o];
            r += pk * w23;
        }
        float bbo = 0.f;
        #pragma unroll
        for (int j = 0; j < K2_; ++j) bbo += b2[j] * W3[j * NOUT_ + o];
        out[(size_t)b * NOUT_ + o] = r + (float)n * bbo + b3[o];
    }
}

extern "C" void kernel_launch(void* const* d_in, const int* in_sizes, int n_in,
                              void* d_out, int out_size, void* d_ws, size_t ws_size,
                              hipStream_t stream) {
    const float* X        = (const float*)d_in[0];
    const int*   setSizes = (const int*)  d_in[1];
    const float* W1       = (const float*)d_in[2];
    const float* b1       = (const float*)d_in[3];
    const float* W2       = (const float*)d_in[4];
    const float* b2       = (const float*)d_in[5];
    const float* W3       = (const float*)d_in[6];
    const float* b3       = (const float*)d_in[7];
    float* out = (float*)d_out;

    hipLaunchKernelGGL(setembed_fused, dim3(B_), dim3(256), 0, stream,
                       X, setSizes, W1, b1, W2, b2, W3, b3, out);
}

// Round 4
// 343.647 us; speedup vs baseline: 1.2812x; 1.0008x over previous
//
#include <hip/hip_runtime.h>
#include <hip/hip_bf16.h>

#define B_    2048
#define S_    512
#define NFT_  64
#define K1_   16
#define K2_   12
#define NOUT_ 32

typedef __attribute__((ext_vector_type(8))) short bf16x8;  // 8 bf16 = 4 VGPRs
typedef __attribute__((ext_vector_type(4))) float f32x4;

static __device__ __forceinline__ short f2bf1(float x) {
    union { __hip_bfloat16 h; short s; } u;
    u.h = __float2bfloat16(x);
    return u.s;
}

// 8 fp32 -> 8 bf16 via packed RNE converts (v_cvt_pk_bf16_f32)
static __device__ __forceinline__ bf16x8 cvt8(float4 lo, float4 hi) {
    union { bf16x8 v; __hip_bfloat162 h[4]; } u;
    u.h[0] = __float22bfloat162_rn(make_float2(lo.x, lo.y));
    u.h[1] = __float22bfloat162_rn(make_float2(lo.z, lo.w));
    u.h[2] = __float22bfloat162_rn(make_float2(hi.x, hi.y));
    u.h[3] = __float22bfloat162_rn(make_float2(hi.z, hi.w));
    return u.v;
}

// One block per batch. 4 waves; wave w owns 16-row tiles t = w, w+4, ...
// A-frag: lane (quad=L>>4, m=L&15) holds A[row=m][k=quad*8+j] -> direct global loads
// B-frag: W1 column m in 8+8 VGPRs. C-frag: reg i -> row=quad*4+i, col=m.
__global__ __launch_bounds__(256) void setembed_fused(
    const float* __restrict__ X, const int* __restrict__ setSizes,
    const float* __restrict__ W1, const float* __restrict__ b1,
    const float* __restrict__ W2, const float* __restrict__ b2,
    const float* __restrict__ W3, const float* __restrict__ b3,
    float* __restrict__ out)
{
    __shared__ float w23s[K1_ * NOUT_];   // W2@W3, built cooperatively
    __shared__ float bbs[NOUT_];          // b2@W3
    __shared__ float red[4][K1_];

    const int t    = threadIdx.x;
    const int b    = blockIdx.x;
    const int wave = t >> 6;
    const int lane = t & 63;
    const int m    = lane & 15;
    const int quad = lane >> 4;

    const int n = setSizes[b];

    // ---- cooperative epilogue weights: 2 entries/thread, 12 FMAs each ----
    {
        const int k = t >> 5, o = t & 31;           // k in 0..7
        float s0 = 0.f, s1 = 0.f;
        #pragma unroll
        for (int j = 0; j < K2_; ++j) {
            const float w3 = W3[j * NOUT_ + o];
            s0 += W2[k * K2_ + j] * w3;
            s1 += W2[(k + 8) * K2_ + j] * w3;
        }
        w23s[t] = s0;
        w23s[t + 256] = s1;
        if (t < NOUT_) {
            float sb = 0.f;
            #pragma unroll
            for (int j = 0; j < K2_; ++j) sb += b2[j] * W3[j * NOUT_ + t];
            bbs[t] = sb;
        }
    }

    // ---- W1 as two B-fragments; bias for owned column ----
    bf16x8 wf0, wf1;
    #pragma unroll
    for (int j = 0; j < 8; ++j) {
        wf0[j] = f2bf1(W1[(     quad * 8 + j) * K1_ + m]);
        wf1[j] = f2bf1(W1[(32 + quad * 8 + j) * K1_ + m]);
    }
    const float bk = b1[m];

    float pool = 0.f;
    const int ntiles = (n + 15) >> 4;
    const float* lp = X + (size_t)b * S_ * NFT_ + (size_t)m * NFT_ + quad * 8;

    // ---- software-pipelined tile loop (2-deep, loads of t+4 before cvt of t) ----
    float4 c0, c1, c2, c3;
    int tl = wave;
    if (tl < ntiles) {
        const float* p = lp + (size_t)tl * (16 * NFT_);
        c0 = *(const float4*)(p);      c1 = *(const float4*)(p + 4);
        c2 = *(const float4*)(p + 32); c3 = *(const float4*)(p + 36);
    }
    while (tl < ntiles) {
        const int nx = tl + 4;
        float4 d0, d1, d2, d3;
        if (nx < ntiles) {
            const float* p = lp + (size_t)nx * (16 * NFT_);
            d0 = *(const float4*)(p);      d1 = *(const float4*)(p + 4);
            d2 = *(const float4*)(p + 32); d3 = *(const float4*)(p + 36);
        }

        bf16x8 a0 = cvt8(c0, c1);
        bf16x8 a1 = cvt8(c2, c3);
        f32x4 c = {0.f, 0.f, 0.f, 0.f};
        c = __builtin_amdgcn_mfma_f32_16x16x32_bf16(a0, wf0, c, 0, 0, 0);
        c = __builtin_amdgcn_mfma_f32_16x16x32_bf16(a1, wf1, c, 0, 0, 0);

        const int r0 = tl * 16 + quad * 4;
        #pragma unroll
        for (int i = 0; i < 4; ++i) {
            float h = c[i] + bk;
            h = h > 0.f ? h : 0.f;
            pool += (r0 + i < n) ? h : 0.f;
        }
        c0 = d0; c1 = d1; c2 = d2; c3 = d3;
        tl = nx;
    }

    // ---- reduce over quad groups, then across waves ----
    pool += __shfl_xor(pool, 16, 64);
    pool += __shfl_xor(pool, 32, 64);
    if (lane < K1_) red[wave][lane] = pool;
    __syncthreads();

    if (t < NOUT_) {
        const int o = t;
        float r = 0.f;
        #pragma unroll
        for (int k = 0; k < K1_; ++k) {
            const float pk = red[0][k] + red[1][k] + red[2][k] + red[3][k];
            r += pk * w23s[k * NOUT_ + o];
        }
        out[(size_t)b * NOUT_ + o] = r + (float)n * bbs[o] + b3[o];
    }
}

extern "C" void kernel_launch(void* const* d_in, const int* in_sizes, int n_in,
                              void* d_out, int out_size, void* d_ws, size_t ws_size,
                              hipStream_t stream) {
    const float* X        = (const float*)d_in[0];
    const int*   setSizes = (const int*)  d_in[1];
    const float* W1       = (const float*)d_in[2];
    const float* b1       = (const float*)d_in[3];
    const float* W2       = (const float*)d_in[4];
    const float* b2       = (const float*)d_in[5];
    const float* W3       = (const float*)d_in[6];
    const float* b3       = (const float*)d_in[7];
    float* out = (float*)d_out;

    hipLaunchKernelGGL(setembed_fused, dim3(B_), dim3(256), 0, stream,
                       X, setSizes, W1, b1, W2, b2, W3, b3, out);
}

// Round 5
// 342.717 us; speedup vs baseline: 1.2847x; 1.0027x over previous
//
#include <hip/hip_runtime.h>
#include <hip/hip_bf16.h>

#define B_    2048
#define S_    512
#define NFT_  64
#define K1_   16
#define K2_   12
#define NOUT_ 32

typedef __attribute__((ext_vector_type(8))) short bf16x8;  // 8 bf16 = 4 VGPRs
typedef __attribute__((ext_vector_type(4))) float f32x4;

static __device__ __forceinline__ short f2bf1(float x) {
    union { __hip_bfloat16 h; short s; } u;
    u.h = __float2bfloat16(x);
    return u.s;
}

// 8 fp32 -> 8 bf16 via packed RNE converts (v_cvt_pk_bf16_f32)
static __device__ __forceinline__ bf16x8 cvt8(float4 lo, float4 hi) {
    union { bf16x8 v; __hip_bfloat162 h[4]; } u;
    u.h[0] = __float22bfloat162_rn(make_float2(lo.x, lo.y));
    u.h[1] = __float22bfloat162_rn(make_float2(lo.z, lo.w));
    u.h[2] = __float22bfloat162_rn(make_float2(hi.x, hi.y));
    u.h[3] = __float22bfloat162_rn(make_float2(hi.z, hi.w));
    return u.v;
}

// One block per batch. 4 waves; wave w owns 16-row tiles t = w, w+4, ...
// A-frag: lane (quad=L>>4, m=L&15) holds A[row=m][k=quad*8+j] -> direct global loads
// B-frag: W1 column m, staged once per block via LDS (bf16 frag layout).
// C-frag: reg i -> row=quad*4+i, col=m.
__global__ __launch_bounds__(256) void setembed_fused(
    const float* __restrict__ X, const int* __restrict__ setSizes,
    const float* __restrict__ W1, const float* __restrict__ b1,
    const float* __restrict__ W2, const float* __restrict__ b2,
    const float* __restrict__ W3, const float* __restrict__ b3,
    float* __restrict__ out)
{
    __shared__ __align__(16) short w1bf[K1_][NFT_];  // [col][feature] bf16, 2 KB
    __shared__ float w23s[K1_ * NOUT_];              // W2@W3
    __shared__ float bbs[NOUT_];                     // b2@W3
    __shared__ float red[4][K1_];

    const int t    = threadIdx.x;
    const int b    = blockIdx.x;
    const int wave = t >> 6;
    const int lane = t & 63;
    const int m    = lane & 15;
    const int quad = lane >> 4;

    const int n = setSizes[b];

    // ---- stage W1 (4 KB, L2-hot) into LDS bf16 frag layout: 1 dwordx4/thread ----
    {
        float4 v = *((const float4*)W1 + t);         // elements 4t..4t+3
        int e = t * 4;
        int f  = e >> 4;                             // feature (row of W1)
        int c0 = e & 15;                             // col base: 0,4,8,12
        w1bf[c0 + 0][f] = f2bf1(v.x);
        w1bf[c0 + 1][f] = f2bf1(v.y);
        w1bf[c0 + 2][f] = f2bf1(v.z);
        w1bf[c0 + 3][f] = f2bf1(v.w);
    }

    // ---- cooperative epilogue weights: 2 entries/thread, 12 FMAs each ----
    {
        const int k = t >> 5, o = t & 31;            // k in 0..7
        float s0 = 0.f, s1 = 0.f;
        #pragma unroll
        for (int j = 0; j < K2_; ++j) {
            const float w3 = W3[j * NOUT_ + o];
            s0 += W2[k * K2_ + j] * w3;
            s1 += W2[(k + 8) * K2_ + j] * w3;
        }
        w23s[t] = s0;
        w23s[t + 256] = s1;
        if (t < NOUT_) {
            float sb = 0.f;
            #pragma unroll
            for (int j = 0; j < K2_; ++j) sb += b2[j] * W3[j * NOUT_ + t];
            bbs[t] = sb;
        }
    }
    __syncthreads();

    // ---- W1 B-fragments: 2 x ds_read_b128 (broadcast within quad groups) ----
    const bf16x8 wf0 = *(const bf16x8*)&w1bf[m][     quad * 8];
    const bf16x8 wf1 = *(const bf16x8*)&w1bf[m][32 + quad * 8];
    const float bk = b1[m];

    float pool = 0.f;
    const int ntiles = (n + 15) >> 4;
    const float* lp = X + (size_t)b * S_ * NFT_ + (size_t)m * NFT_ + quad * 8;

    // ---- software-pipelined tile loop (2-deep) ----
    float4 c0, c1, c2, c3;
    int tl = wave;
    if (tl < ntiles) {
        const float* p = lp + (size_t)tl * (16 * NFT_);
        c0 = *(const float4*)(p);      c1 = *(const float4*)(p + 4);
        c2 = *(const float4*)(p + 32); c3 = *(const float4*)(p + 36);
    }
    while (tl < ntiles) {
        const int nx = tl + 4;
        float4 d0, d1, d2, d3;
        if (nx < ntiles) {
            const float* p = lp + (size_t)nx * (16 * NFT_);
            d0 = *(const float4*)(p);      d1 = *(const float4*)(p + 4);
            d2 = *(const float4*)(p + 32); d3 = *(const float4*)(p + 36);
        }

        bf16x8 a0 = cvt8(c0, c1);
        bf16x8 a1 = cvt8(c2, c3);
        f32x4 c = {0.f, 0.f, 0.f, 0.f};
        c = __builtin_amdgcn_mfma_f32_16x16x32_bf16(a0, wf0, c, 0, 0, 0);
        c = __builtin_amdgcn_mfma_f32_16x16x32_bf16(a1, wf1, c, 0, 0, 0);

        const int r0 = tl * 16 + quad * 4;
        #pragma unroll
        for (int i = 0; i < 4; ++i) {
            float h = c[i] + bk;
            h = h > 0.f ? h : 0.f;
            pool += (r0 + i < n) ? h : 0.f;
        }
        c0 = d0; c1 = d1; c2 = d2; c3 = d3;
        tl = nx;
    }

    // ---- reduce over quad groups, then across waves ----
    pool += __shfl_xor(pool, 16, 64);
    pool += __shfl_xor(pool, 32, 64);
    if (lane < K1_) red[wave][lane] = pool;
    __syncthreads();

    if (t < NOUT_) {
        const int o = t;
        float r = 0.f;
        #pragma unroll
        for (int k = 0; k < K1_; ++k) {
            const float pk = red[0][k] + red[1][k] + red[2][k] + red[3][k];
            r += pk * w23s[k * NOUT_ + o];
        }
        out[(size_t)b * NOUT_ + o] = r + (float)n * bbs[o] + b3[o];
    }
}

extern "C" void kernel_launch(void* const* d_in, const int* in_sizes, int n_in,
                              void* d_out, int out_size, void* d_ws, size_t ws_size,
                              hipStream_t stream) {
    const float* X        = (const float*)d_in[0];
    const int*   setSizes = (const int*)  d_in[1];
    const float* W1       = (const float*)d_in[2];
    const float* b1       = (const float*)d_in[3];
    const float* W2       = (const float*)d_in[4];
    const float* b2       = (const float*)d_in[5];
    const float* W3       = (const float*)d_in[6];
    const float* b3       = (const float*)d_in[7];
    float* out = (float*)d_out;

    hipLaunchKernelGGL(setembed_fused, dim3(B_), dim3(256), 0, stream,
                       X, setSizes, W1, b1, W2, b2, W3, b3, out);
}